// Round 1
// baseline (1196.500 us; speedup 1.0000x reference)
//
#include <hip/hip_runtime.h>

#define NQ     12
#define DIM    (1 << NQ)   // 4096 amplitudes
#define DEPTH  6

// ---------------------------------------------------------------------------
// Layout conventions (wire i <-> state-index bit (11-i); wire 0 = MSB):
//   Even ("A") sweep: lane t, register j  <->  amplitude q = (t<<6) | j
//   Odd  ("B") sweep: lane t, register j  <->  amplitude q = (j<<6) | t
// LDS holds one float array (re OR im) at a time in the swizzled layout
//   f(q) = q ^ ((q>>6)&63)   (keeps every b32 phase <=2-way bank aliased)
// The 11-CNOT chain maps index q -> C(q), bit k of C(q) = XOR of q bits k..11
// (suffix-xor). It is folded into the ODD sweep's store addresses: amp q is
// stored at f(C(q)), so CNOTs cost zero instructions.
// ---------------------------------------------------------------------------

__device__ __host__ __forceinline__ constexpr int sufx6(int v) {
  int a = v ^ (v >> 1);
  a ^= a >> 2;
  a ^= a >> 4;
  return a & 63;
}
// float-index constant for CNOT-folded store (odd sweeps), register part:
// f(C(q)) = (SJ<<6) ^ SJ ^ ST(t) ^ (parity(j)?63:0), SJ = sufx6(j)
__device__ __host__ __forceinline__ constexpr int KCf(int j) {
  const int sj = sufx6(j);
  const int p  = __builtin_popcount((unsigned)j) & 1;
  return (sj << 6) ^ sj ^ (p ? 63 : 0);
}
// float-index constant for B-layout load: f((j<<6)|t) = ((j<<6)^j) ^ t
__device__ __host__ __forceinline__ constexpr int KBf(int j) { return (j << 6) ^ j; }

// Apply one fused 2x2 complex gate on local bit B of the 64-amp register tile.
// All indices compile-time -> pure VGPR, 16 FMA-class ops per pair.
template <int B>
__device__ __forceinline__ void gate6(float (&re)[64], float (&im)[64],
                                      float u00r, float u00i, float u01r, float u01i,
                                      float u10r, float u10i, float u11r, float u11i) {
#pragma unroll
  for (int m = 0; m < 32; ++m) {
    const int lo = m & ((1 << B) - 1);
    const int j0 = ((m >> B) << (B + 1)) | lo;  // local bit B == 0
    const int j1 = j0 | (1 << B);               // local bit B == 1
    const float ar = re[j0], ai = im[j0];
    const float br = re[j1], bi = im[j1];
    float nr0 = u00r * ar; nr0 = fmaf(-u00i, ai, nr0); nr0 = fmaf(u01r, br, nr0); nr0 = fmaf(-u01i, bi, nr0);
    float ni0 = u00r * ai; ni0 = fmaf( u00i, ar, ni0); ni0 = fmaf(u01r, bi, ni0); ni0 = fmaf( u01i, br, ni0);
    float nr1 = u10r * ar; nr1 = fmaf(-u10i, ai, nr1); nr1 = fmaf(u11r, br, nr1); nr1 = fmaf(-u11i, bi, nr1);
    float ni1 = u10r * ai; ni1 = fmaf( u10i, ar, ni1); ni1 = fmaf(u11r, bi, ni1); ni1 = fmaf( u11i, br, ni1);
    re[j0] = nr0; im[j0] = ni0;
    re[j1] = nr1; im[j1] = ni1;
  }
}

__global__ __launch_bounds__(64, 2) void qsim_kernel(const float* __restrict__ x,
                                                     const float* __restrict__ params,
                                                     float* __restrict__ out) {
  __shared__ float sm[DIM];               // 16 KiB transpose buffer (re or im per phase)
  __shared__ float uTab[DEPTH * NQ * 8];  // 72 fused 2x2 complex gates

  const int t = threadIdx.x;  // lane 0..63
  const int b = blockIdx.x;   // batch element

  // ---- precompute fused gates U = RX(p2) * RZ(p1) * RY(p0) into LDS ----
  for (int g = t; g < DEPTH * NQ; g += 64) {
    const int d = g / NQ, w = g % NQ;
    const float py = params[(d * NQ + w) * 3 + 0];
    const float pz = params[(d * NQ + w) * 3 + 1];
    const float px = params[(d * NQ + w) * 3 + 2];
    float sa, ca, sb, cb, sg, cg;
    __sincosf(py * 0.5f, &sa, &ca);
    __sincosf(pz * 0.5f, &sb, &cb);
    __sincosf(px * 0.5f, &sg, &cg);
    // RZ*RY entries: A=(ca*cb,-ca*sb) B=(-sa*cb,sa*sb) C=(sa*cb,sa*sb) D=(ca*cb,ca*sb)
    const float Ar = ca * cb, Ai = -ca * sb;
    const float Br = -sa * cb, Bi = sa * sb;
    const float Cr = sa * cb, Ci = sa * sb;
    const float Dr = ca * cb, Di = ca * sb;
    float* u = &uTab[g * 8];
    u[0] = cg * Ar + sg * Ci;   u[1] = cg * Ai - sg * Cr;   // u00
    u[2] = cg * Br + sg * Di;   u[3] = cg * Bi - sg * Dr;   // u01
    u[4] = sg * Ai + cg * Cr;   u[5] = -sg * Ar + cg * Ci;  // u10
    u[6] = sg * Bi + cg * Dr;   u[7] = -sg * Br + cg * Di;  // u11
  }

  // ---- product-state init (post RX-encoding), directly in A-layout regs ----
  float re[64], im[64];
  {
    float cs[NQ], sn[NQ];
#pragma unroll
    for (int i = 0; i < NQ; ++i) __sincosf(x[b * NQ + i] * 0.5f, &sn[i], &cs[i]);
    // high 6 bits (= lane t) are wires 0..5: wire i <-> t bit (5-i)
    float hm = 1.0f;
#pragma unroll
    for (int i = 0; i < 6; ++i) hm *= ((t >> (5 - i)) & 1) ? sn[i] : cs[i];
    // low 6 bits (= reg j) are wires 6..11: j bit bb <-> wire 11-bb; build products in-place
    re[0] = hm;
#pragma unroll
    for (int bb = 0; bb < 6; ++bb) {
#pragma unroll
      for (int j = 0; j < (1 << bb); ++j) {
        re[j | (1 << bb)] = re[j] * sn[11 - bb];
        re[j] = re[j] * cs[11 - bb];
      }
    }
    // amplitude = magnitude * (-i)^popcount(q)
    const int pt = __popc(t);
#pragma unroll
    for (int j = 0; j < 64; ++j) {
      const float m = re[j];
      const int k = (pt + __popc(j)) & 3;
      re[j] = (k & 1) ? 0.0f : ((k & 2) ? -m : m);
      im[j] = (k & 1) ? ((k & 2) ? m : -m) : 0.0f;
    }
  }

  __syncthreads();  // uTab ready

  const int KAf = (t << 6) ^ t;  // A store/load float-index base
  const int STf = sufx6(t);      // lane part of CNOT-folded store address

#pragma unroll 1
  for (int sw = 0; sw < 12; ++sw) {
    const int d = sw >> 1;
    const bool odd = sw & 1;

    // ---- 6 fused gates on the local bits ----
    // even sweep: local bit bb <-> global bit bb  <-> wire 11-bb
    // odd  sweep: local bit bb <-> global bit bb+6 <-> wire 5-bb
#define APPLY_GATE(BB)                                                        \
    {                                                                         \
      const int w = odd ? (5 - (BB)) : (11 - (BB));                           \
      const float* u = &uTab[(d * NQ + w) * 8];                               \
      gate6<BB>(re, im, u[0], u[1], u[2], u[3], u[4], u[5], u[6], u[7]);      \
    }
    APPLY_GATE(0)
    APPLY_GATE(1)
    APPLY_GATE(2)
    APPLY_GATE(3)
    APPLY_GATE(4)
    APPLY_GATE(5)
#undef APPLY_GATE

    // ---- boundary: transpose A<->B layout through LDS (re phase, then im) ----
    // odd stores fold the full 11-CNOT chain of layer d into the address.
    if (odd) {
#pragma unroll
      for (int j = 0; j < 64; ++j) sm[STf ^ KCf(j)] = re[j];
    } else {
#pragma unroll
      for (int j = 0; j < 64; ++j) sm[KAf ^ j] = re[j];
    }
    __syncthreads();
    if (odd) {  // next sweep (or final output) uses A layout
#pragma unroll
      for (int j = 0; j < 64; ++j) re[j] = sm[KAf ^ j];
    } else {    // next sweep uses B layout
#pragma unroll
      for (int j = 0; j < 64; ++j) re[j] = sm[t ^ KBf(j)];
    }
    __syncthreads();
    if (odd) {
#pragma unroll
      for (int j = 0; j < 64; ++j) sm[STf ^ KCf(j)] = im[j];
    } else {
#pragma unroll
      for (int j = 0; j < 64; ++j) sm[KAf ^ j] = im[j];
    }
    __syncthreads();
    if (odd) {
#pragma unroll
      for (int j = 0; j < 64; ++j) im[j] = sm[KAf ^ j];
    } else {
#pragma unroll
      for (int j = 0; j < 64; ++j) im[j] = sm[t ^ KBf(j)];
    }
    __syncthreads();
  }

  // ---- output: <Z_w> = sum_q |amp(q)|^2 * (-1)^(bit(11-w) of q), A layout ----
  float tot = 0.0f;
  float sv[6] = {0.f, 0.f, 0.f, 0.f, 0.f, 0.f};  // signed sums over reg-index bits
#pragma unroll
  for (int j = 0; j < 64; ++j) {
    const float p = fmaf(re[j], re[j], im[j] * im[j]);
    tot += p;
#pragma unroll
    for (int bb = 0; bb < 6; ++bb) {
      if ((j >> bb) & 1) sv[bb] -= p; else sv[bb] += p;  // compile-time sign
    }
  }
  float v[12];
#pragma unroll
  for (int w = 0; w < 6; ++w) v[w] = ((t >> (5 - w)) & 1) ? -tot : tot;  // wires 0..5: lane bit
#pragma unroll
  for (int w = 6; w < 12; ++w) v[w] = sv[11 - w];                        // wires 6..11: reg bit
#pragma unroll
  for (int w = 0; w < 12; ++w) {
#pragma unroll
    for (int o = 32; o > 0; o >>= 1) v[w] += __shfl_xor(v[w], o);
  }
  if (t == 0) {
#pragma unroll
    for (int w = 0; w < 12; ++w) out[b * NQ + w] = v[w];
  }
}

extern "C" void kernel_launch(void* const* d_in, const int* in_sizes, int n_in,
                              void* d_out, int out_size, void* d_ws, size_t ws_size,
                              hipStream_t stream) {
  const float* x      = (const float*)d_in[0];
  const float* params = (const float*)d_in[1];
  float* out          = (float*)d_out;
  const int B = in_sizes[0] / NQ;  // 4096
  qsim_kernel<<<B, 64, 0, stream>>>(x, params, out);
}